// Round 15
// baseline (34.534 us; speedup 1.0000x reference)
//
#include <hip/hip_runtime.h>

// SymbolicTraversal: out[b, n] = max(0, max_{e: type[e]==r_index[b], dst[e]==n} h[b, src[e]])
//
// R14: R13 + denser segments (NB1 512 -> 256).
//   790K records / (400 buckets x 256 blocks) = lambda 7.7 per 15-slot segment:
//   scan utilization 24% -> 48%, phase2 passes 8 -> 4, store traffic 13.1 -> 6.6MB.
//   phase1: 256 x 1024 (262K threads, R8-proven sufficient TLP), stream edges,
//           relation->batch bitmask filter, LDS queues -> 64B segment flush.
//   phase2: 400 x 1024, batch-major bucket decode (b = bid % B) for XCD-local
//           h gathers (R13 win), wave-shaped (segment,word) apply, 16KB LDS slice,
//           plain coalesced store (out never read).
// Record: ((dst & 4095) << 17) | src  (needs N <= 2^17, guarded).
// Overflow: per-block ws list (~0.6% rate at lambda 7.7, ~2K records total); panic
// (> OVCAP) -> phase2 re-streams bucket edges (max idempotent). Fallback for odd shapes.

typedef int v4i __attribute__((ext_vector_type(4)));

#define NB1 256
#define TH1 1024
#define TH2 1024
#define QCAP 15
#define CSHIFT 12
#define MAXNBKT 448
#define OVCAP 16384

__global__ __launch_bounds__(TH1)
void phase1_kernel(const int* __restrict__ edge_index, // [2][E]
                   const int* __restrict__ etype,      // [E]
                   const int* __restrict__ r_index,    // [B]
                   unsigned int* __restrict__ ovcnt,   // [NB1] raw counts
                   uint2* __restrict__ ovrec,          // [NB1][OVCAP]
                   unsigned int* __restrict__ store,   // [nbkt][NB1][16]
                   int B, int N, int E, int nchunk, int nbkt) {
    __shared__ unsigned int smask[64];
    __shared__ unsigned int lcnt[MAXNBKT];
    __shared__ unsigned int lq[MAXNBKT * QCAP];
    __shared__ unsigned int sov;

    const int t = threadIdx.x;
    const int bid = blockIdx.x;
    if (t < 64) {
        unsigned int m = 0;
        for (int b = 0; b < B; ++b)
            if (r_index[b] == t) m |= (1u << b);
        smask[t] = m;
    }
    for (int i = t; i < nbkt; i += TH1) lcnt[i] = 0;
    if (t == 0) sov = 0;
    __syncthreads();

    const int* __restrict__ src = edge_index;
    const int* __restrict__ dst = edge_index + E;
    const unsigned int cmask = (1u << CSHIFT) - 1u;
    const int nq = E >> 2;

    for (int q = bid * TH1 + t; q < nq; q += NB1 * TH1) {
        v4i tv = __builtin_nontemporal_load(reinterpret_cast<const v4i*>(etype) + q);
        v4i sv = __builtin_nontemporal_load(reinterpret_cast<const v4i*>(src) + q);
        v4i dv = __builtin_nontemporal_load(reinterpret_cast<const v4i*>(dst) + q);
        #pragma unroll
        for (int i = 0; i < 4; ++i) {
            unsigned int ty = (unsigned int)tv[i];
            unsigned int m = (ty < 64u) ? smask[ty] : 0u;
            if (!m) continue;
            unsigned int d = (unsigned int)dv[i];
            unsigned int s = (unsigned int)sv[i];
            unsigned int rec = ((d & cmask) << 17) | s;
            int cb = (int)(d >> CSHIFT);
            do {
                int b = __builtin_ctz(m); m &= m - 1;
                int bkt = b * nchunk + cb;
                unsigned int pos = atomicAdd(&lcnt[bkt], 1u);
                if (pos < QCAP) {
                    lq[bkt * QCAP + pos] = rec;
                } else {
                    unsigned int p2 = atomicAdd(&sov, 1u);
                    if (p2 < OVCAP) {
                        uint2 rr; rr.x = (d << 5) | (unsigned int)b; rr.y = s;
                        ovrec[(size_t)bid * OVCAP + p2] = rr;
                    } // beyond OVCAP: dropped; raw count > OVCAP triggers panic re-stream
                }
            } while (m);
        }
    }
    if (bid == 0) {  // tail edges (E % 4)
        for (int e = (nq << 2) + t; e < E; e += TH1) {
            unsigned int ty = (unsigned int)etype[e];
            unsigned int m = (ty < 64u) ? smask[ty] : 0u;
            unsigned int d = (unsigned int)dst[e];
            unsigned int s = (unsigned int)src[e];
            unsigned int rec = ((d & cmask) << 17) | s;
            int cb = (int)(d >> CSHIFT);
            while (m) {
                int b = __builtin_ctz(m); m &= m - 1;
                int bkt = b * nchunk + cb;
                unsigned int pos = atomicAdd(&lcnt[bkt], 1u);
                if (pos < QCAP) {
                    lq[bkt * QCAP + pos] = rec;
                } else {
                    unsigned int p2 = atomicAdd(&sov, 1u);
                    if (p2 < OVCAP) {
                        uint2 rr; rr.x = (d << 5) | (unsigned int)b; rr.y = s;
                        ovrec[(size_t)bid * OVCAP + p2] = rr;
                    }
                }
            }
        }
    }
    __syncthreads();

    if (t == 0) ovcnt[bid] = sov;  // raw (not clamped): >OVCAP means panic

    // Flush: each bucket -> one full 64B line. 16 lanes/bucket, 4 buckets/wave.
    const int wid = t >> 6, lane = t & 63;
    const int sub = lane >> 4, word = lane & 15;
    for (int k0 = wid * 4; k0 < nbkt; k0 += (TH1 / 64) * 4) {
        int k = k0 + sub;
        if (k < nbkt) {
            unsigned int n = lcnt[k]; if (n > QCAP) n = QCAP;
            unsigned int val = (word == 0) ? n : lq[k * QCAP + (word - 1)];
            store[((size_t)k * NB1 + bid) * 16 + word] = val;
        }
    }
}

__global__ __launch_bounds__(TH2)
void phase2_kernel(const float* __restrict__ h,
                   const unsigned int* __restrict__ store,
                   const unsigned int* __restrict__ ovcnt,
                   const uint2* __restrict__ ovrec,
                   const int* __restrict__ edge_index,
                   const int* __restrict__ etype,
                   const int* __restrict__ r_index,
                   int B, int N, int E, int nchunk,
                   int* __restrict__ out) {
    __shared__ int slice[1 << CSHIFT];  // 16KB
    __shared__ int spanic;

    const int t = threadIdx.x;
    // XCD-locality decode: blocks with the same batch b land on the same XCD
    // (bid % 8 heuristic; B % 8 == 0 guarded at launch).
    const int b = blockIdx.x % B;
    const int c = blockIdx.x / B;
    const int k = b * nchunk + c;       // bucket (store layout unchanged)
    const int csz = 1 << CSHIFT;
    const unsigned int cmask = (1u << CSHIFT) - 1u;

    for (int i = t; i < csz; i += TH2) slice[i] = 0;
    if (t == 0) spanic = 0;
    __syncthreads();

    const unsigned int* __restrict__ base = store + (size_t)k * NB1 * 16;
    const float* __restrict__ hb = h + (size_t)b * N;

    // Wave-shaped segment apply: lane reads word (t&15) of segment (t>>4).
    const int lane16 = t & 15;
    const int srcLane = (t & 63) & ~15;
    #pragma unroll 2
    for (int pass = 0; pass < NB1 / (TH2 / 16); ++pass) {
        int seg = pass * (TH2 / 16) + (t >> 4);
        unsigned int w = base[(size_t)seg * 16 + lane16];
        unsigned int n = (unsigned int)__shfl((int)w, srcLane, 64);
        if (n > QCAP) n = QCAP;
        if (lane16 >= 1 && (unsigned int)lane16 <= n) {
            int s  = (int)(w & 0x1FFFFu);
            int ld = (int)(w >> 17);
            atomicMax(&slice[ld], __float_as_int(hb[s]));
        }
    }

    // Overflow lists: thread r owns list r (~8 records/list at lambda 7.7).
    for (int r = t; r < NB1; r += TH2) {
        unsigned int raw = ovcnt[r];
        if (raw > OVCAP) { atomicOr(&spanic, 1); raw = OVCAP; }
        const uint2* __restrict__ rp = ovrec + (size_t)r * OVCAP;
        for (unsigned int i = 0; i < raw; ++i) {
            uint2 rr = rp[i];
            int bb = (int)(rr.x & 31u);
            unsigned int d = rr.x >> 5;
            if (bb == b && (int)(d >> CSHIFT) == c)
                atomicMax(&slice[d & cmask], __float_as_int(hb[rr.y]));
        }
    }
    __syncthreads();

    if (spanic) {  // ultra-rare: re-stream all edges for this bucket (idempotent max)
        const int rb = r_index[b];
        const int* __restrict__ src = edge_index;
        const int* __restrict__ dst = edge_index + E;
        for (int e = t; e < E; e += TH2) {
            if (etype[e] == rb) {
                unsigned int d = (unsigned int)dst[e];
                if ((int)(d >> CSHIFT) == c)
                    atomicMax(&slice[d & cmask], __float_as_int(hb[src[e]]));
            }
        }
        __syncthreads();
    }

    // Plain coalesced store (out never read; covers clamp floor + empty segments).
    const int d0 = c << CSHIFT;
    int cnt = N - d0; if (cnt > csz) cnt = csz;
    int* __restrict__ ob = out + (size_t)b * N + d0;
    for (int i = t; i < cnt; i += TH2) ob[i] = slice[i];
}

// ===== Fallback for unsupported shapes / tiny ws =====

__global__ __launch_bounds__(256)
void zero_out_kernel(int* __restrict__ out, int n) {
    int i = (blockIdx.x * 256 + threadIdx.x) * 4;
    if (i + 3 < n) {
        v4i z = {0, 0, 0, 0};
        *reinterpret_cast<v4i*>(out + i) = z;
    } else {
        for (int j = i; j < n && j >= 0; ++j) out[j] = 0;
    }
}

__global__ __launch_bounds__(256)
void traverse_direct(const float* __restrict__ h,
                     const int* __restrict__ edge_index,
                     const int* __restrict__ etype,
                     const int* __restrict__ r_index,
                     int* __restrict__ out, int B, int N, int E) {
    __shared__ unsigned int smask[64];
    if (threadIdx.x < 64) {
        unsigned int m = 0;
        for (int b = 0; b < B; ++b)
            if (r_index[b] == (int)threadIdx.x) m |= (1u << b);
        smask[threadIdx.x] = m;
    }
    __syncthreads();
    const int* __restrict__ src = edge_index;
    const int* __restrict__ dst = edge_index + E;
    int e = blockIdx.x * blockDim.x + threadIdx.x;
    if (e < E) {
        unsigned int ty = (unsigned int)etype[e];
        unsigned int m = (ty < 64u) ? smask[ty] : 0u;
        while (m) {
            int b = __builtin_ctz(m); m &= m - 1;
            float v = h[(size_t)b * N + src[e]];
            atomicMax(out + (size_t)b * N + dst[e], __float_as_int(v));
        }
    }
}

extern "C" void kernel_launch(void* const* d_in, const int* in_sizes, int n_in,
                              void* d_out, int out_size, void* d_ws, size_t ws_size,
                              hipStream_t stream) {
    const float* h          = (const float*)d_in[0];
    const int*   edge_index = (const int*)d_in[1];
    const int*   etype      = (const int*)d_in[2];
    const int*   r_index    = (const int*)d_in[3];

    const int B = in_sizes[3];
    const int N = in_sizes[0] / B;
    const int E = in_sizes[2];
    const int nchunk = (N + (1 << CSHIFT) - 1) >> CSHIFT;
    const int nbkt = B * nchunk;
    int* out_i = (int*)d_out;

    // ws layout: ovcnt u32[NB1] (4KB pad) | store [nbkt][NB1][16] u32 | ovrec [NB1][OVCAP] uint2
    unsigned int* ovcnt = (unsigned int*)d_ws;
    unsigned int* store = ovcnt + 1024;
    const size_t store_words = (size_t)(nbkt > 0 ? nbkt : 1) * NB1 * 16;
    uint2* ovrec = (uint2*)(store + store_words);
    const size_t need_ws = 4096 + store_words * 4 + (size_t)NB1 * OVCAP * 8;

    const bool fast = (N <= (1 << 17)) && (B <= 32) && (B % 8 == 0) && (nbkt >= 1) &&
                      (nbkt <= MAXNBKT) && (ws_size >= need_ws) && (E >= 4) &&
                      (out_size == B * N);
    if (fast) {
        phase1_kernel<<<NB1, TH1, 0, stream>>>(
            edge_index, etype, r_index, ovcnt, ovrec, store,
            B, N, E, nchunk, nbkt);
        phase2_kernel<<<nbkt, TH2, 0, stream>>>(
            h, store, ovcnt, ovrec, edge_index, etype, r_index,
            B, N, E, nchunk, out_i);
    } else {
        const int nz = (out_size + 1023) / 1024;
        zero_out_kernel<<<nz, 256, 0, stream>>>(out_i, out_size);
        traverse_direct<<<(E + 255) / 256, 256, 0, stream>>>(
            h, edge_index, etype, r_index, out_i, B, N, E);
    }
}

// Round 16
// 26.404 us; speedup vs baseline: 1.3079x; 1.3079x over previous
//
#include <hip/hip_runtime.h>

// SymbolicTraversal: out[b, n] = max(0, max_{e: type[e]==r_index[b], dst[e]==n} h[b, src[e]])
//
// R15: exact R13 structure (best: 28.7us), with nontemporal load hints REMOVED from
// the phase1 edge streams (nt bypasses L2 aggregation; R0->R1 record shows nt was
// never a win; edge data is read-once so L2 pollution is harmless).
//   phase1: 512 x 1024, stream edges, relation->batch bitmask filter, LDS queues ->
//           64B segment flush {count, <=15 records}, no global atomics.
//   phase2: 400 x 1024, batch-major bucket decode (b = bid % B) for XCD-local
//           h gathers, wave-shaped (segment,word) apply, 16KB LDS slice,
//           plain coalesced store (out never read).
// Record: ((dst & 4095) << 17) | src  (needs N <= 2^17, guarded).
// Overflow: per-block ws list; panic (> OVCAP) -> re-stream bucket edges (idempotent).

typedef int v4i __attribute__((ext_vector_type(4)));

#define NB1 512
#define TH1 1024
#define TH2 1024
#define QCAP 15
#define CSHIFT 12
#define MAXNBKT 448
#define OVCAP 16384

__global__ __launch_bounds__(TH1)
void phase1_kernel(const int* __restrict__ edge_index, // [2][E]
                   const int* __restrict__ etype,      // [E]
                   const int* __restrict__ r_index,    // [B]
                   unsigned int* __restrict__ ovcnt,   // [NB1] raw counts
                   uint2* __restrict__ ovrec,          // [NB1][OVCAP]
                   unsigned int* __restrict__ store,   // [nbkt][NB1][16]
                   int B, int N, int E, int nchunk, int nbkt) {
    __shared__ unsigned int smask[64];
    __shared__ unsigned int lcnt[MAXNBKT];
    __shared__ unsigned int lq[MAXNBKT * QCAP];
    __shared__ unsigned int sov;

    const int t = threadIdx.x;
    const int bid = blockIdx.x;
    if (t < 64) {
        unsigned int m = 0;
        for (int b = 0; b < B; ++b)
            if (r_index[b] == t) m |= (1u << b);
        smask[t] = m;
    }
    for (int i = t; i < nbkt; i += TH1) lcnt[i] = 0;
    if (t == 0) sov = 0;
    __syncthreads();

    const int* __restrict__ src = edge_index;
    const int* __restrict__ dst = edge_index + E;
    const unsigned int cmask = (1u << CSHIFT) - 1u;
    const int nq = E >> 2;

    for (int q = bid * TH1 + t; q < nq; q += NB1 * TH1) {
        v4i tv = reinterpret_cast<const v4i*>(etype)[q];
        v4i sv = reinterpret_cast<const v4i*>(src)[q];
        v4i dv = reinterpret_cast<const v4i*>(dst)[q];
        #pragma unroll
        for (int i = 0; i < 4; ++i) {
            unsigned int ty = (unsigned int)tv[i];
            unsigned int m = (ty < 64u) ? smask[ty] : 0u;
            if (!m) continue;
            unsigned int d = (unsigned int)dv[i];
            unsigned int s = (unsigned int)sv[i];
            unsigned int rec = ((d & cmask) << 17) | s;
            int cb = (int)(d >> CSHIFT);
            do {
                int b = __builtin_ctz(m); m &= m - 1;
                int bkt = b * nchunk + cb;
                unsigned int pos = atomicAdd(&lcnt[bkt], 1u);
                if (pos < QCAP) {
                    lq[bkt * QCAP + pos] = rec;
                } else {
                    unsigned int p2 = atomicAdd(&sov, 1u);
                    if (p2 < OVCAP) {
                        uint2 rr; rr.x = (d << 5) | (unsigned int)b; rr.y = s;
                        ovrec[(size_t)bid * OVCAP + p2] = rr;
                    } // beyond OVCAP: dropped; raw count > OVCAP triggers panic re-stream
                }
            } while (m);
        }
    }
    if (bid == 0) {  // tail edges (E % 4)
        for (int e = (nq << 2) + t; e < E; e += TH1) {
            unsigned int ty = (unsigned int)etype[e];
            unsigned int m = (ty < 64u) ? smask[ty] : 0u;
            unsigned int d = (unsigned int)dst[e];
            unsigned int s = (unsigned int)src[e];
            unsigned int rec = ((d & cmask) << 17) | s;
            int cb = (int)(d >> CSHIFT);
            while (m) {
                int b = __builtin_ctz(m); m &= m - 1;
                int bkt = b * nchunk + cb;
                unsigned int pos = atomicAdd(&lcnt[bkt], 1u);
                if (pos < QCAP) {
                    lq[bkt * QCAP + pos] = rec;
                } else {
                    unsigned int p2 = atomicAdd(&sov, 1u);
                    if (p2 < OVCAP) {
                        uint2 rr; rr.x = (d << 5) | (unsigned int)b; rr.y = s;
                        ovrec[(size_t)bid * OVCAP + p2] = rr;
                    }
                }
            }
        }
    }
    __syncthreads();

    if (t == 0) ovcnt[bid] = sov;  // raw (not clamped): >OVCAP means panic

    // Flush: each bucket -> one full 64B line. 16 lanes/bucket, 4 buckets/wave.
    const int wid = t >> 6, lane = t & 63;
    const int sub = lane >> 4, word = lane & 15;
    for (int k0 = wid * 4; k0 < nbkt; k0 += (TH1 / 64) * 4) {
        int k = k0 + sub;
        if (k < nbkt) {
            unsigned int n = lcnt[k]; if (n > QCAP) n = QCAP;
            unsigned int val = (word == 0) ? n : lq[k * QCAP + (word - 1)];
            store[((size_t)k * NB1 + bid) * 16 + word] = val;
        }
    }
}

__global__ __launch_bounds__(TH2)
void phase2_kernel(const float* __restrict__ h,
                   const unsigned int* __restrict__ store,
                   const unsigned int* __restrict__ ovcnt,
                   const uint2* __restrict__ ovrec,
                   const int* __restrict__ edge_index,
                   const int* __restrict__ etype,
                   const int* __restrict__ r_index,
                   int B, int N, int E, int nchunk,
                   int* __restrict__ out) {
    __shared__ int slice[1 << CSHIFT];  // 16KB
    __shared__ int spanic;

    const int t = threadIdx.x;
    // XCD-locality decode: blocks with the same batch b land on the same XCD
    // (bid % 8 heuristic; B % 8 == 0 guarded at launch).
    const int b = blockIdx.x % B;
    const int c = blockIdx.x / B;
    const int k = b * nchunk + c;       // bucket (store layout unchanged)
    const int csz = 1 << CSHIFT;
    const unsigned int cmask = (1u << CSHIFT) - 1u;

    for (int i = t; i < csz; i += TH2) slice[i] = 0;
    if (t == 0) spanic = 0;
    __syncthreads();

    const unsigned int* __restrict__ base = store + (size_t)k * NB1 * 16;
    const float* __restrict__ hb = h + (size_t)b * N;

    // Wave-shaped segment apply: lane reads word (t&15) of segment (t>>4).
    const int lane16 = t & 15;
    const int srcLane = (t & 63) & ~15;
    #pragma unroll 2
    for (int pass = 0; pass < NB1 / (TH2 / 16); ++pass) {
        int seg = pass * (TH2 / 16) + (t >> 4);
        unsigned int w = base[(size_t)seg * 16 + lane16];
        unsigned int n = (unsigned int)__shfl((int)w, srcLane, 64);
        if (n > QCAP) n = QCAP;
        if (lane16 >= 1 && (unsigned int)lane16 <= n) {
            int s  = (int)(w & 0x1FFFFu);
            int ld = (int)(w >> 17);
            atomicMax(&slice[ld], __float_as_int(hb[s]));
        }
    }

    // Overflow lists: thread r owns list r (counts ~0 in practice).
    for (int r = t; r < NB1; r += TH2) {
        unsigned int raw = ovcnt[r];
        if (raw > OVCAP) { atomicOr(&spanic, 1); raw = OVCAP; }
        const uint2* __restrict__ rp = ovrec + (size_t)r * OVCAP;
        for (unsigned int i = 0; i < raw; ++i) {
            uint2 rr = rp[i];
            int bb = (int)(rr.x & 31u);
            unsigned int d = rr.x >> 5;
            if (bb == b && (int)(d >> CSHIFT) == c)
                atomicMax(&slice[d & cmask], __float_as_int(hb[rr.y]));
        }
    }
    __syncthreads();

    if (spanic) {  // ultra-rare: re-stream all edges for this bucket (idempotent max)
        const int rb = r_index[b];
        const int* __restrict__ src = edge_index;
        const int* __restrict__ dst = edge_index + E;
        for (int e = t; e < E; e += TH2) {
            if (etype[e] == rb) {
                unsigned int d = (unsigned int)dst[e];
                if ((int)(d >> CSHIFT) == c)
                    atomicMax(&slice[d & cmask], __float_as_int(hb[src[e]]));
            }
        }
        __syncthreads();
    }

    // Plain coalesced store (out never read; covers clamp floor + empty segments).
    const int d0 = c << CSHIFT;
    int cnt = N - d0; if (cnt > csz) cnt = csz;
    int* __restrict__ ob = out + (size_t)b * N + d0;
    for (int i = t; i < cnt; i += TH2) ob[i] = slice[i];
}

// ===== Fallback for unsupported shapes / tiny ws =====

__global__ __launch_bounds__(256)
void zero_out_kernel(int* __restrict__ out, int n) {
    int i = (blockIdx.x * 256 + threadIdx.x) * 4;
    if (i + 3 < n) {
        v4i z = {0, 0, 0, 0};
        *reinterpret_cast<v4i*>(out + i) = z;
    } else {
        for (int j = i; j < n && j >= 0; ++j) out[j] = 0;
    }
}

__global__ __launch_bounds__(256)
void traverse_direct(const float* __restrict__ h,
                     const int* __restrict__ edge_index,
                     const int* __restrict__ etype,
                     const int* __restrict__ r_index,
                     int* __restrict__ out, int B, int N, int E) {
    __shared__ unsigned int smask[64];
    if (threadIdx.x < 64) {
        unsigned int m = 0;
        for (int b = 0; b < B; ++b)
            if (r_index[b] == (int)threadIdx.x) m |= (1u << b);
        smask[threadIdx.x] = m;
    }
    __syncthreads();
    const int* __restrict__ src = edge_index;
    const int* __restrict__ dst = edge_index + E;
    int e = blockIdx.x * blockDim.x + threadIdx.x;
    if (e < E) {
        unsigned int ty = (unsigned int)etype[e];
        unsigned int m = (ty < 64u) ? smask[ty] : 0u;
        while (m) {
            int b = __builtin_ctz(m); m &= m - 1;
            float v = h[(size_t)b * N + src[e]];
            atomicMax(out + (size_t)b * N + dst[e], __float_as_int(v));
        }
    }
}

extern "C" void kernel_launch(void* const* d_in, const int* in_sizes, int n_in,
                              void* d_out, int out_size, void* d_ws, size_t ws_size,
                              hipStream_t stream) {
    const float* h          = (const float*)d_in[0];
    const int*   edge_index = (const int*)d_in[1];
    const int*   etype      = (const int*)d_in[2];
    const int*   r_index    = (const int*)d_in[3];

    const int B = in_sizes[3];
    const int N = in_sizes[0] / B;
    const int E = in_sizes[2];
    const int nchunk = (N + (1 << CSHIFT) - 1) >> CSHIFT;
    const int nbkt = B * nchunk;
    int* out_i = (int*)d_out;

    // ws layout: ovcnt u32[NB1] (4KB pad) | store [nbkt][NB1][16] u32 | ovrec [NB1][OVCAP] uint2
    unsigned int* ovcnt = (unsigned int*)d_ws;
    unsigned int* store = ovcnt + 1024;
    const size_t store_words = (size_t)(nbkt > 0 ? nbkt : 1) * NB1 * 16;
    uint2* ovrec = (uint2*)(store + store_words);
    const size_t need_ws = 4096 + store_words * 4 + (size_t)NB1 * OVCAP * 8;

    const bool fast = (N <= (1 << 17)) && (B <= 32) && (B % 8 == 0) && (nbkt >= 1) &&
                      (nbkt <= MAXNBKT) && (ws_size >= need_ws) && (E >= 4) &&
                      (out_size == B * N);
    if (fast) {
        phase1_kernel<<<NB1, TH1, 0, stream>>>(
            edge_index, etype, r_index, ovcnt, ovrec, store,
            B, N, E, nchunk, nbkt);
        phase2_kernel<<<nbkt, TH2, 0, stream>>>(
            h, store, ovcnt, ovrec, edge_index, etype, r_index,
            B, N, E, nchunk, out_i);
    } else {
        const int nz = (out_size + 1023) / 1024;
        zero_out_kernel<<<nz, 256, 0, stream>>>(out_i, out_size);
        traverse_direct<<<(E + 255) / 256, 256, 0, stream>>>(
            h, edge_index, etype, r_index, out_i, B, N, E);
    }
}